// Round 11
// baseline (1640.451 us; speedup 1.0000x reference)
//
#include <hip/hip_runtime.h>
#include <math.h>

#define TOKENS   8192
#define DMODEL   1024
#define HDIM     2048
#define NEXP     8
#define NSH      2
#define NGRP     10
#define R_ROUTED 16384
#define R_TOTAL  32768

typedef float  f32x4  __attribute__((ext_vector_type(4)));
typedef __bf16 bf16x8 __attribute__((ext_vector_type(8)));
typedef unsigned short u16x8 __attribute__((ext_vector_type(8)));

typedef __attribute__((address_space(1))) const void as1_void;
typedef __attribute__((address_space(3))) void as3_void;
#define GLOAD16(g, l) __builtin_amdgcn_global_load_lds((as1_void*)(g), (as3_void*)(l), 16, 0, 0)

__device__ __forceinline__ unsigned short f2bf(float f) {
  unsigned int u = __float_as_uint(f);
  u += 0x7fffu + ((u >> 16) & 1u);
  return (unsigned short)(u >> 16);
}
__device__ __forceinline__ float bf2f(unsigned short u) {
  return __uint_as_float(((unsigned int)u) << 16);
}

// ---- batched transpose fp32 (R x C) -> bf16 (C x R), 64x64 tiles ----
__global__ __launch_bounds__(256) void transpose_cvt64_kernel(
    const float* __restrict__ s0, const float* __restrict__ s1,
    const float* __restrict__ s2, const float* __restrict__ s3,
    unsigned short* __restrict__ dst, int R, int C, int n0, int n1) {
  __shared__ float tile[64][65];
  const int z = blockIdx.z;
  const size_t msz = (size_t)R * C;
  const float* src;
  if (z < n0) src = s0 + (size_t)z * msz;
  else if (z < n0 + n1) src = s1 + (size_t)(z - n0) * msz;
  else if (z < n0 + n1 + 8) src = s2 + (size_t)(z - n0 - n1) * msz;
  else src = s3 + (size_t)(z - n0 - n1 - 8) * msz;
  unsigned short* d = dst + (size_t)z * msz;

  const int c0 = blockIdx.x * 64, r0 = blockIdx.y * 64;
  const int tid = threadIdx.x;
  const int tx = tid & 15, ty = tid >> 4;
  #pragma unroll
  for (int rr = 0; rr < 4; ++rr) {
    const int row = ty + rr * 16;
    const float4 v = *reinterpret_cast<const float4*>(&src[(size_t)(r0 + row) * C + c0 + tx * 4]);
    tile[row][tx * 4 + 0] = v.x;
    tile[row][tx * 4 + 1] = v.y;
    tile[row][tx * 4 + 2] = v.z;
    tile[row][tx * 4 + 3] = v.w;
  }
  __syncthreads();
  const int oc = tid >> 2, og = tid & 3;
  u16x8 u0, u1;
  #pragma unroll
  for (int e = 0; e < 8; ++e) u0[e] = f2bf(tile[og * 16 + e][oc]);
  #pragma unroll
  for (int e = 0; e < 8; ++e) u1[e] = f2bf(tile[og * 16 + 8 + e][oc]);
  unsigned short* dp = &d[(size_t)(c0 + oc) * R + r0 + og * 16];
  *reinterpret_cast<u16x8*>(dp) = u0;
  *reinterpret_cast<u16x8*>(dp + 8) = u1;
}

// ---- gate + x->bf16 conversion fused.  4 tokens / 256-thr block ----

__global__ __launch_bounds__(256) void gate_kernel(const float* __restrict__ x,
                                                   const float* __restrict__ gw,
                                                   const float* __restrict__ gb,
                                                   int* __restrict__ topk_idx,
                                                   float* __restrict__ topk_w,
                                                   int* __restrict__ counts,
                                                   unsigned short* __restrict__ xb) {
  const int t = blockIdx.x * 4 + (threadIdx.x >> 6);
  const int lane = threadIdx.x & 63;
  const float* xr = x + (size_t)t * DMODEL;
  unsigned short* xbr = xb + (size_t)t * DMODEL;
  float acc[NEXP];
  #pragma unroll
  for (int e = 0; e < NEXP; ++e) acc[e] = 0.f;
  #pragma unroll
  for (int j = 0; j < 4; ++j) {
    const int d = j * 256 + lane * 4;
    const float4 v = *reinterpret_cast<const float4*>(&xr[d]);
    ushort4 o;
    o.x = f2bf(v.x); o.y = f2bf(v.y); o.z = f2bf(v.z); o.w = f2bf(v.w);
    *reinterpret_cast<ushort4*>(&xbr[d]) = o;
    #pragma unroll
    for (int q = 0; q < 4; ++q) {
      const float xv = (&v.x)[q];
      const float* g = gw + (size_t)(d + q) * NEXP;
      #pragma unroll
      for (int e = 0; e < NEXP; ++e) acc[e] += xv * g[e];
    }
  }
  #pragma unroll
  for (int e = 0; e < NEXP; ++e) {
    float v = acc[e];
    v += __shfl_down(v, 32); v += __shfl_down(v, 16); v += __shfl_down(v, 8);
    v += __shfl_down(v, 4);  v += __shfl_down(v, 2);  v += __shfl_down(v, 1);
    acc[e] = v;
  }
  if (lane == 0) {
    float p[NEXP];
    float mx = -1e30f;
    #pragma unroll
    for (int e = 0; e < NEXP; ++e) { acc[e] += gb[e]; mx = fmaxf(mx, acc[e]); }
    float s = 0.f;
    #pragma unroll
    for (int e = 0; e < NEXP; ++e) { p[e] = expf(acc[e] - mx); s += p[e]; }
    const float inv = 1.f / s;
    #pragma unroll
    for (int e = 0; e < NEXP; ++e) p[e] *= inv;
    int i1 = 0; float v1 = p[0];
    #pragma unroll
    for (int e = 1; e < NEXP; ++e) if (p[e] > v1) { v1 = p[e]; i1 = e; }
    int i2 = -1; float v2 = -1e30f;
    #pragma unroll
    for (int e = 0; e < NEXP; ++e) if (e != i1 && p[e] > v2) { v2 = p[e]; i2 = e; }
    topk_idx[t * 2 + 0] = i1; topk_w[t * 2 + 0] = v1;
    topk_idx[t * 2 + 1] = i2; topk_w[t * 2 + 1] = v2;
    atomicAdd(&counts[i1], 1);
    atomicAdd(&counts[i2], 1);
  }
}

__global__ void offs_kernel(const int* __restrict__ counts, int* __restrict__ offs) {
  if (threadIdx.x == 0 && blockIdx.x == 0) {
    int cum = 0;
    for (int e = 0; e < NEXP; ++e) { offs[e] = cum; cum += counts[e]; }
    offs[8] = R_ROUTED;
    offs[9] = R_ROUTED + TOKENS;
    offs[10] = R_TOTAL;
  }
}

__global__ __launch_bounds__(256) void scatter_kernel(const int* __restrict__ topk_idx,
                                                      const int* __restrict__ offs,
                                                      int* __restrict__ cursors,
                                                      int* __restrict__ row_token,
                                                      int* __restrict__ tok_rows) {
  const int t = blockIdx.x * blockDim.x + threadIdx.x;
  if (t >= TOKENS) return;
  #pragma unroll
  for (int k = 0; k < 2; ++k) {
    const int e = topk_idx[t * 2 + k];
    const int pos = atomicAdd(&cursors[e], 1);
    const int r = offs[e] + pos;
    row_token[r] = t;
    tok_rows[t * 2 + k] = r;
  }
  row_token[R_ROUTED + t] = t;
  row_token[R_ROUTED + TOKENS + t] = t;
}

// ---- grouped GEMM 1: glu = silu(X W1 + b1) * (X W2 + b2) ----
// R7 champion structure (128m x 64n dual-B, BK=64, 256 thr, 4 waves 2Mx2N,
// single-buffer A, 2 barriers/K-tile, 8-chunk XOR swizzle) with ONE change:
// B1/B2 fragments load DIRECTLY global->VGPR (no LDS) — halves LDS traffic,
// which R10's pipe arithmetic showed is the binding resource (LDS 1130 cyc
// vs MFMA 310 cyc per block-K-tile).  B loads drain at the same pre-barrier
// vmcnt(0) the schedule already pays.

__global__ __launch_bounds__(256, 2) void gemm1_kernel(
    const unsigned short* __restrict__ xb,
    const unsigned short* __restrict__ w1t,
    const unsigned short* __restrict__ w2t,
    const float* __restrict__ rb1, const float* __restrict__ sb1,
    const float* __restrict__ rb2, const float* __restrict__ sb2,
    const int* __restrict__ offs,
    const int* __restrict__ row_token,
    unsigned short* __restrict__ glu) {
  const int g = blockIdx.z;
  const int off_g = offs[g];
  const int n_g = offs[g + 1] - off_g;
  const int m0 = blockIdx.x * 128;
  if (m0 >= n_g) return;
  const int n0 = blockIdx.y * 64;

  __shared__ __align__(16) unsigned short Abuf[128 * 64];   // 16 KB only

  const int tid = threadIdx.x;
  const int lane = tid & 63;
  const int wid = tid >> 6;
  const int wm = wid >> 1, wn = wid & 1;
  const int l15 = lane & 15, kq = lane >> 4;

  const unsigned short* w1g = w1t + (size_t)g * HDIM * DMODEL;
  const unsigned short* w2g = w2t + (size_t)g * HDIM * DMODEL;

  // A staging: 128 rows x 8 chunks = 1024 chunks, 4 rounds of 256
  const unsigned short* srcA[4]; int dA[4];
  #pragma unroll
  for (int r = 0; r < 4; ++r) {
    const int chunk = r * 256 + tid, row = chunk >> 3, j = chunk & 7;
    int ar = m0 + row; if (ar > n_g - 1) ar = n_g - 1;
    srcA[r] = xb + (size_t)row_token[off_g + ar] * DMODEL + ((j ^ (row & 7)) << 3);
    dA[r] = (r * 256 + (tid & ~63)) << 3;
  }
  // B row pointers (per-lane, direct global)
  const unsigned short* bp1[2]; const unsigned short* bp2[2];
  #pragma unroll
  for (int ni = 0; ni < 2; ++ni) {
    const int row = n0 + wn * 32 + ni * 16 + l15;
    bp1[ni] = w1g + (size_t)row * DMODEL;
    bp2[ni] = w2g + (size_t)row * DMODEL;
  }

  f32x4 acc1[4][2], acc2[4][2];
  const f32x4 zero = {0.f, 0.f, 0.f, 0.f};
  #pragma unroll
  for (int i = 0; i < 4; ++i)
    #pragma unroll
    for (int j = 0; j < 2; ++j) { acc1[i][j] = zero; acc2[i][j] = zero; }

  for (int k0 = 0; k0 < DMODEL; k0 += 64) {
    __syncthreads();
    #pragma unroll
    for (int r = 0; r < 4; ++r) GLOAD16(srcA[r] + k0, &Abuf[dA[r]]);
    // B fragments for this K-tile -> registers (drained by the same barrier)
    bf16x8 B1r[2][2], B2r[2][2];   // [ks][ni]
    #pragma unroll
    for (int ks = 0; ks < 2; ++ks) {
      const int koff = k0 + ((ks * 4 + kq) << 3);
      #pragma unroll
      for (int ni = 0; ni < 2; ++ni) {
        B1r[ks][ni] = *reinterpret_cast<const bf16x8*>(bp1[ni] + koff);
        B2r[ks][ni] = *reinterpret_cast<const bf16x8*>(bp2[ni] + koff);
      }
    }
    __syncthreads();
    #pragma unroll
    for (int ks = 0; ks < 2; ++ks) {
      const int kc = ks * 4 + kq;
      bf16x8 a[4];
      #pragma unroll
      for (int mi = 0; mi < 4; ++mi) {
        const int row = wm * 64 + mi * 16 + l15;
        a[mi] = *reinterpret_cast<const bf16x8*>(&Abuf[row * 64 + ((kc ^ (row & 7)) << 3)]);
      }
      #pragma unroll
      for (int mi = 0; mi < 4; ++mi)
        #pragma unroll
        for (int ni = 0; ni < 2; ++ni) {
          acc1[mi][ni] = __builtin_amdgcn_mfma_f32_16x16x32_bf16(a[mi], B1r[ks][ni], acc1[mi][ni], 0, 0, 0);
          acc2[mi][ni] = __builtin_amdgcn_mfma_f32_16x16x32_bf16(a[mi], B2r[ks][ni], acc2[mi][ni], 0, 0, 0);
        }
    }
  }

  const float* b1p = (g < NEXP) ? (rb1 + (size_t)g * HDIM) : (sb1 + (size_t)(g - NEXP) * HDIM);
  const float* b2p = (g < NEXP) ? (rb2 + (size_t)g * HDIM) : (sb2 + (size_t)(g - NEXP) * HDIM);

  #pragma unroll
  for (int mi = 0; mi < 4; ++mi) {
    #pragma unroll
    for (int r = 0; r < 4; ++r) {
      const int m = m0 + wm * 64 + mi * 16 + kq * 4 + r;
      if (m < n_g) {
        #pragma unroll
        for (int ni = 0; ni < 2; ++ni) {
          const int n = n0 + wn * 32 + ni * 16 + l15;
          const float x1 = acc1[mi][ni][r] + b1p[n];
          const float x2 = acc2[mi][ni][r] + b2p[n];
          glu[(size_t)(off_g + m) * HDIM + n] = f2bf((x1 / (1.f + expf(-x1))) * x2);
        }
      }
    }
  }
}

// ---- grouped GEMM 2: y = (glu W3 + b3) bf16, no atomics ----
// 128x128, BK=64, 256 thr (4 waves 2Mx2N, per-wave 64x64).  A via LDS,
// B (w3t) fragments direct global->VGPR.  LDS read/write 48 KB vs MFMA
// 620 cyc per block-K-tile -> MFMA-bound by design.

__global__ __launch_bounds__(256, 2) void gemm2_kernel(
    const unsigned short* __restrict__ glu,
    const unsigned short* __restrict__ w3t,
    const float* __restrict__ rb3, const float* __restrict__ sb3,
    const int* __restrict__ offs,
    unsigned short* __restrict__ y) {
  const int g = blockIdx.z;
  const int off_g = offs[g];
  const int n_g = offs[g + 1] - off_g;
  const int m0 = blockIdx.x * 128;
  if (m0 >= n_g) return;
  const int n0 = blockIdx.y * 128;

  __shared__ __align__(16) unsigned short Abuf[128 * 64];   // 16 KB

  const int tid = threadIdx.x;
  const int lane = tid & 63;
  const int wid = tid >> 6;
  const int wm = wid >> 1, wn = wid & 1;
  const int l15 = lane & 15, kq = lane >> 4;

  const unsigned short* w3g = w3t + (size_t)g * DMODEL * HDIM;

  const unsigned short* srcA[4]; int dA[4];
  #pragma unroll
  for (int r = 0; r < 4; ++r) {
    const int chunk = r * 256 + tid, row = chunk >> 3, j = chunk & 7;
    int ar = m0 + row; if (ar > n_g - 1) ar = n_g - 1;
    srcA[r] = glu + (size_t)(off_g + ar) * HDIM + ((j ^ (row & 7)) << 3);
    dA[r] = (r * 256 + (tid & ~63)) << 3;
  }
  const unsigned short* bp[4];
  #pragma unroll
  for (int ni = 0; ni < 4; ++ni) {
    const int row = n0 + wn * 64 + ni * 16 + l15;
    bp[ni] = w3g + (size_t)row * HDIM;
  }

  f32x4 acc[4][4];
  const f32x4 zero = {0.f, 0.f, 0.f, 0.f};
  #pragma unroll
  for (int i = 0; i < 4; ++i)
    #pragma unroll
    for (int j = 0; j < 4; ++j) acc[i][j] = zero;

  for (int k0 = 0; k0 < HDIM; k0 += 64) {
    __syncthreads();
    #pragma unroll
    for (int r = 0; r < 4; ++r) GLOAD16(srcA[r] + k0, &Abuf[dA[r]]);
    bf16x8 Br[2][4];   // [ks][ni]
    #pragma unroll
    for (int ks = 0; ks < 2; ++ks) {
      const int koff = k0 + ((ks * 4 + kq) << 3);
      #pragma unroll
      for (int ni = 0; ni < 4; ++ni)
        Br[ks][ni] = *reinterpret_cast<const bf16x8*>(bp[ni] + koff);
    }
    __syncthreads();
    #pragma unroll
    for (int ks = 0; ks < 2; ++ks) {
      const int kc = ks * 4 + kq;
      bf16x8 a[4];
      #pragma unroll
      for (int mi = 0; mi < 4; ++mi) {
        const int row = wm * 64 + mi * 16 + l15;
        a[mi] = *reinterpret_cast<const bf16x8*>(&Abuf[row * 64 + ((kc ^ (row & 7)) << 3)]);
      }
      #pragma unroll
      for (int mi = 0; mi < 4; ++mi)
        #pragma unroll
        for (int ni = 0; ni < 4; ++ni)
          acc[mi][ni] = __builtin_amdgcn_mfma_f32_16x16x32_bf16(a[mi], Br[ks][ni], acc[mi][ni], 0, 0, 0);
    }
  }

  const float* b3p = (g < NEXP) ? (rb3 + (size_t)g * DMODEL) : (sb3 + (size_t)(g - NEXP) * DMODEL);

  #pragma unroll
  for (int mi = 0; mi < 4; ++mi) {
    #pragma unroll
    for (int r = 0; r < 4; ++r) {
      const int m = m0 + wm * 64 + mi * 16 + kq * 4 + r;
      if (m < n_g) {
        unsigned short* yrow = y + (size_t)(off_g + m) * DMODEL;
        #pragma unroll
        for (int ni = 0; ni < 4; ++ni) {
          const int n = n0 + wn * 64 + ni * 16 + l15;
          yrow[n] = f2bf(acc[mi][ni][r] + b3p[n]);
        }
      }
    }
  }
}

// ---- reduce: out[t] = w0*y[r0] + w1*y[r1] + 0.5*y[sh0] + 0.5*y[sh1] ----

__global__ __launch_bounds__(256) void reduce_kernel(const unsigned short* __restrict__ y,
                                                     const int* __restrict__ tok_rows,
                                                     const float* __restrict__ topk_w,
                                                     float* __restrict__ out) {
  const int t = blockIdx.x * 2 + (threadIdx.x >> 7);
  const int col = (threadIdx.x & 127) * 8;
  const int r0 = tok_rows[t * 2 + 0], r1 = tok_rows[t * 2 + 1];
  const float w0 = topk_w[t * 2 + 0], w1 = topk_w[t * 2 + 1];

  float o[8];
  #pragma unroll
  for (int e = 0; e < 8; ++e) o[e] = 0.f;
  auto addrow = [&](const unsigned short* p, float w) {
    const u16x8 v = *reinterpret_cast<const u16x8*>(p);
    #pragma unroll
    for (int e = 0; e < 8; ++e) o[e] += w * bf2f(v[e]);
  };
  addrow(y + (size_t)r0 * DMODEL + col, w0);
  addrow(y + (size_t)r1 * DMODEL + col, w1);
  addrow(y + (size_t)(R_ROUTED + t) * DMODEL + col, 0.5f);
  addrow(y + (size_t)(R_ROUTED + TOKENS + t) * DMODEL + col, 0.5f);

  float4* op = reinterpret_cast<float4*>(out + (size_t)t * DMODEL + col);
  op[0] = make_float4(o[0], o[1], o[2], o[3]);
  op[1] = make_float4(o[4], o[5], o[6], o[7]);
}

// ---------------- launch ----------------

extern "C" void kernel_launch(void* const* d_in, const int* in_sizes, int n_in,
                              void* d_out, int out_size, void* d_ws, size_t ws_size,
                              hipStream_t stream) {
  const float* x      = (const float*)d_in[0];
  const float* gate_w = (const float*)d_in[1];
  const float* gate_b = (const float*)d_in[2];
  const float* rw1    = (const float*)d_in[3];
  const float* rb1    = (const float*)d_in[4];
  const float* rw2    = (const float*)d_in[5];
  const float* rb2    = (const float*)d_in[6];
  const float* rw3    = (const float*)d_in[7];
  const float* rb3    = (const float*)d_in[8];
  const float* sw1    = (const float*)d_in[9];
  const float* sb1    = (const float*)d_in[10];
  const float* sw2    = (const float*)d_in[11];
  const float* sb2    = (const float*)d_in[12];
  const float* sw3    = (const float*)d_in[13];
  const float* sb3    = (const float*)d_in[14];
  float* out = (float*)d_out;

  // workspace layout.  y ALIASES w1t/w2t (dead after gemm1; stream-ordered).
  const size_t XB_OFF   = 0;
  const size_t W1T_OFF  = XB_OFF  + (size_t)TOKENS * DMODEL * 2;
  const size_t W3T_OFF  = W1T_OFF + (size_t)2 * NGRP * HDIM * DMODEL * 2;
  const size_t GLU_OFF  = W3T_OFF + (size_t)NGRP * DMODEL * HDIM * 2;
  const size_t Y_OFF    = W1T_OFF;                       // alias over w1t/w2t
  const size_t RTOK_OFF = GLU_OFF + (size_t)R_TOTAL * HDIM * 2;
  const size_t TKI_OFF  = RTOK_OFF + (size_t)R_TOTAL * 4;
  const size_t TKW_OFF  = TKI_OFF + (size_t)TOKENS * 2 * 4;
  const size_t TRW_OFF  = TKW_OFF + (size_t)TOKENS * 2 * 4;
  const size_t META_OFF = TRW_OFF + (size_t)TOKENS * 2 * 4;
  const size_t NEED     = META_OFF + 256;
  if (ws_size < NEED) return;

  char* ws = (char*)d_ws;
  unsigned short* xb   = (unsigned short*)(ws + XB_OFF);
  unsigned short* w1t  = (unsigned short*)(ws + W1T_OFF);   // 20 mats: w1 (10) then w2 (10)
  unsigned short* w2t  = w1t + (size_t)NGRP * HDIM * DMODEL;
  unsigned short* w3t  = (unsigned short*)(ws + W3T_OFF);
  unsigned short* glu  = (unsigned short*)(ws + GLU_OFF);
  unsigned short* yy   = (unsigned short*)(ws + Y_OFF);
  int*   row_token = (int*)(ws + RTOK_OFF);
  int*   topk_idx  = (int*)(ws + TKI_OFF);
  float* topk_w    = (float*)(ws + TKW_OFF);
  int*   tok_rows  = (int*)(ws + TRW_OFF);
  int*   counts    = (int*)(ws + META_OFF);
  int*   offs      = counts + 16;
  int*   cursors   = counts + 32;

  hipMemsetAsync(counts, 0, 192, stream);

  transpose_cvt64_kernel<<<dim3(HDIM / 64, DMODEL / 64, 20), 256, 0, stream>>>(
      rw1, sw1, rw2, sw2, w1t, DMODEL, HDIM, 8, 2);
  transpose_cvt64_kernel<<<dim3(DMODEL / 64, HDIM / 64, 10), 256, 0, stream>>>(
      rw3, sw3, rw3, rw3, w3t, HDIM, DMODEL, 8, 2);

  gate_kernel<<<TOKENS / 4, 256, 0, stream>>>(x, gate_w, gate_b, topk_idx, topk_w, counts, xb);
  offs_kernel<<<1, 64, 0, stream>>>(counts, offs);
  scatter_kernel<<<TOKENS / 256, 256, 0, stream>>>(topk_idx, offs, cursors,
                                                   row_token, tok_rows);

  gemm1_kernel<<<dim3(TOKENS / 128, HDIM / 64, NGRP), 256, 0, stream>>>(
      xb, w1t, w2t, rb1, sb1, rb2, sb2, offs, row_token, glu);
  gemm2_kernel<<<dim3(TOKENS / 128, DMODEL / 128, NGRP), 256, 0, stream>>>(
      glu, w3t, rb3, sb3, offs, yy);
  reduce_kernel<<<TOKENS / 2, 256, 0, stream>>>(yy, tok_rows, topk_w, out);
}

// Round 12
// 1241.755 us; speedup vs baseline: 1.3211x; 1.3211x over previous
//
#include <hip/hip_runtime.h>
#include <math.h>

#define TOKENS   8192
#define DMODEL   1024
#define HDIM     2048
#define NEXP     8
#define NSH      2
#define NGRP     10
#define R_ROUTED 16384
#define R_TOTAL  32768

typedef float  f32x4  __attribute__((ext_vector_type(4)));
typedef __bf16 bf16x8 __attribute__((ext_vector_type(8)));
typedef unsigned short u16x8 __attribute__((ext_vector_type(8)));

typedef __attribute__((address_space(1))) const void as1_void;
typedef __attribute__((address_space(3))) void as3_void;
#define GLOAD16(g, l) __builtin_amdgcn_global_load_lds((as1_void*)(g), (as3_void*)(l), 16, 0, 0)

__device__ __forceinline__ unsigned short f2bf(float f) {
  unsigned int u = __float_as_uint(f);
  u += 0x7fffu + ((u >> 16) & 1u);
  return (unsigned short)(u >> 16);
}
__device__ __forceinline__ float bf2f(unsigned short u) {
  return __uint_as_float(((unsigned int)u) << 16);
}

// ---- batched transpose fp32 (R x C) -> bf16 (C x R), 64x64 tiles ----
__global__ __launch_bounds__(256) void transpose_cvt64_kernel(
    const float* __restrict__ s0, const float* __restrict__ s1,
    const float* __restrict__ s2, const float* __restrict__ s3,
    unsigned short* __restrict__ dst, int R, int C, int n0, int n1) {
  __shared__ float tile[64][65];
  const int z = blockIdx.z;
  const size_t msz = (size_t)R * C;
  const float* src;
  if (z < n0) src = s0 + (size_t)z * msz;
  else if (z < n0 + n1) src = s1 + (size_t)(z - n0) * msz;
  else if (z < n0 + n1 + 8) src = s2 + (size_t)(z - n0 - n1) * msz;
  else src = s3 + (size_t)(z - n0 - n1 - 8) * msz;
  unsigned short* d = dst + (size_t)z * msz;

  const int c0 = blockIdx.x * 64, r0 = blockIdx.y * 64;
  const int tid = threadIdx.x;
  const int tx = tid & 15, ty = tid >> 4;
  #pragma unroll
  for (int rr = 0; rr < 4; ++rr) {
    const int row = ty + rr * 16;
    const float4 v = *reinterpret_cast<const float4*>(&src[(size_t)(r0 + row) * C + c0 + tx * 4]);
    tile[row][tx * 4 + 0] = v.x;
    tile[row][tx * 4 + 1] = v.y;
    tile[row][tx * 4 + 2] = v.z;
    tile[row][tx * 4 + 3] = v.w;
  }
  __syncthreads();
  const int oc = tid >> 2, og = tid & 3;
  u16x8 u0, u1;
  #pragma unroll
  for (int e = 0; e < 8; ++e) u0[e] = f2bf(tile[og * 16 + e][oc]);
  #pragma unroll
  for (int e = 0; e < 8; ++e) u1[e] = f2bf(tile[og * 16 + 8 + e][oc]);
  unsigned short* dp = &d[(size_t)(c0 + oc) * R + r0 + og * 16];
  *reinterpret_cast<u16x8*>(dp) = u0;
  *reinterpret_cast<u16x8*>(dp + 8) = u1;
}

// ---- gate + x->bf16 conversion fused.  4 tokens / 256-thr block ----

__global__ __launch_bounds__(256) void gate_kernel(const float* __restrict__ x,
                                                   const float* __restrict__ gw,
                                                   const float* __restrict__ gb,
                                                   int* __restrict__ topk_idx,
                                                   float* __restrict__ topk_w,
                                                   int* __restrict__ counts,
                                                   unsigned short* __restrict__ xb) {
  const int t = blockIdx.x * 4 + (threadIdx.x >> 6);
  const int lane = threadIdx.x & 63;
  const float* xr = x + (size_t)t * DMODEL;
  unsigned short* xbr = xb + (size_t)t * DMODEL;
  float acc[NEXP];
  #pragma unroll
  for (int e = 0; e < NEXP; ++e) acc[e] = 0.f;
  #pragma unroll
  for (int j = 0; j < 4; ++j) {
    const int d = j * 256 + lane * 4;
    const float4 v = *reinterpret_cast<const float4*>(&xr[d]);
    ushort4 o;
    o.x = f2bf(v.x); o.y = f2bf(v.y); o.z = f2bf(v.z); o.w = f2bf(v.w);
    *reinterpret_cast<ushort4*>(&xbr[d]) = o;
    #pragma unroll
    for (int q = 0; q < 4; ++q) {
      const float xv = (&v.x)[q];
      const float* g = gw + (size_t)(d + q) * NEXP;
      #pragma unroll
      for (int e = 0; e < NEXP; ++e) acc[e] += xv * g[e];
    }
  }
  #pragma unroll
  for (int e = 0; e < NEXP; ++e) {
    float v = acc[e];
    v += __shfl_down(v, 32); v += __shfl_down(v, 16); v += __shfl_down(v, 8);
    v += __shfl_down(v, 4);  v += __shfl_down(v, 2);  v += __shfl_down(v, 1);
    acc[e] = v;
  }
  if (lane == 0) {
    float p[NEXP];
    float mx = -1e30f;
    #pragma unroll
    for (int e = 0; e < NEXP; ++e) { acc[e] += gb[e]; mx = fmaxf(mx, acc[e]); }
    float s = 0.f;
    #pragma unroll
    for (int e = 0; e < NEXP; ++e) { p[e] = expf(acc[e] - mx); s += p[e]; }
    const float inv = 1.f / s;
    #pragma unroll
    for (int e = 0; e < NEXP; ++e) p[e] *= inv;
    int i1 = 0; float v1 = p[0];
    #pragma unroll
    for (int e = 1; e < NEXP; ++e) if (p[e] > v1) { v1 = p[e]; i1 = e; }
    int i2 = -1; float v2 = -1e30f;
    #pragma unroll
    for (int e = 0; e < NEXP; ++e) if (e != i1 && p[e] > v2) { v2 = p[e]; i2 = e; }
    topk_idx[t * 2 + 0] = i1; topk_w[t * 2 + 0] = v1;
    topk_idx[t * 2 + 1] = i2; topk_w[t * 2 + 1] = v2;
    atomicAdd(&counts[i1], 1);
    atomicAdd(&counts[i2], 1);
  }
}

__global__ void offs_kernel(const int* __restrict__ counts, int* __restrict__ offs) {
  if (threadIdx.x == 0 && blockIdx.x == 0) {
    int cum = 0;
    for (int e = 0; e < NEXP; ++e) { offs[e] = cum; cum += counts[e]; }
    offs[8] = R_ROUTED;
    offs[9] = R_ROUTED + TOKENS;
    offs[10] = R_TOTAL;
  }
}

__global__ __launch_bounds__(256) void scatter_kernel(const int* __restrict__ topk_idx,
                                                      const int* __restrict__ offs,
                                                      int* __restrict__ cursors,
                                                      int* __restrict__ row_token,
                                                      int* __restrict__ tok_rows) {
  const int t = blockIdx.x * blockDim.x + threadIdx.x;
  if (t >= TOKENS) return;
  #pragma unroll
  for (int k = 0; k < 2; ++k) {
    const int e = topk_idx[t * 2 + k];
    const int pos = atomicAdd(&cursors[e], 1);
    const int r = offs[e] + pos;
    row_token[r] = t;
    tok_rows[t * 2 + k] = r;
  }
  row_token[R_ROUTED + t] = t;
  row_token[R_ROUTED + TOKENS + t] = t;
}

// ---- grouped GEMM 1: glu = silu(X W1 + b1) * (X W2 + b2) ----
// R7 champion geometry (128m x 64n dual-B, BK=64, 256 thr, 4 waves 2Mx2N,
// 8-chunk XOR swizzle) upgraded to stage-early DOUBLE-buffer (T3 minimum,
// m248-verified): stage tile kt+1 into buf^1 BEFORE computing buf, ONE
// barrier per K-tile.  Stage latency hides under ~900cy of compute; the
// compiler's vmcnt(0)-before-barrier drain is then free.  LDS 64KB -> 2 blk/CU.

__global__ __launch_bounds__(256, 2) void gemm1_kernel(
    const unsigned short* __restrict__ xb,
    const unsigned short* __restrict__ w1t,
    const unsigned short* __restrict__ w2t,
    const float* __restrict__ rb1, const float* __restrict__ sb1,
    const float* __restrict__ rb2, const float* __restrict__ sb2,
    const int* __restrict__ offs,
    const int* __restrict__ row_token,
    unsigned short* __restrict__ glu) {
  const int g = blockIdx.z;
  const int off_g = offs[g];
  const int n_g = offs[g + 1] - off_g;
  const int m0 = blockIdx.x * 128;
  if (m0 >= n_g) return;
  const int n0 = blockIdx.y * 64;

  __shared__ __align__(16) unsigned short Abuf[2][128 * 64];
  __shared__ __align__(16) unsigned short B1buf[2][64 * 64];
  __shared__ __align__(16) unsigned short B2buf[2][64 * 64];

  const int tid = threadIdx.x;
  const int lane = tid & 63;
  const int wid = tid >> 6;
  const int wm = wid >> 1, wn = wid & 1;
  const int l15 = lane & 15, kq = lane >> 4;

  const unsigned short* w1g = w1t + (size_t)g * HDIM * DMODEL;
  const unsigned short* w2g = w2t + (size_t)g * HDIM * DMODEL;

  const unsigned short* srcA[4]; int dA[4];
  #pragma unroll
  for (int r = 0; r < 4; ++r) {
    const int chunk = r * 256 + tid, row = chunk >> 3, j = chunk & 7;
    int ar = m0 + row; if (ar > n_g - 1) ar = n_g - 1;
    srcA[r] = xb + (size_t)row_token[off_g + ar] * DMODEL + ((j ^ (row & 7)) << 3);
    dA[r] = (r * 256 + (tid & ~63)) << 3;
  }
  const unsigned short* srcB1[2]; const unsigned short* srcB2[2]; int dB[2];
  #pragma unroll
  for (int r = 0; r < 2; ++r) {
    const int chunk = r * 256 + tid, row = chunk >> 3, j = chunk & 7;
    const size_t o = (size_t)(n0 + row) * DMODEL + ((j ^ (row & 7)) << 3);
    srcB1[r] = w1g + o; srcB2[r] = w2g + o;
    dB[r] = (r * 256 + (tid & ~63)) << 3;
  }

  f32x4 acc1[4][2], acc2[4][2];
  const f32x4 zero = {0.f, 0.f, 0.f, 0.f};
  #pragma unroll
  for (int i = 0; i < 4; ++i)
    #pragma unroll
    for (int j = 0; j < 2; ++j) { acc1[i][j] = zero; acc2[i][j] = zero; }

  auto stage = [&](int b, int k0) {
    #pragma unroll
    for (int r = 0; r < 4; ++r) GLOAD16(srcA[r] + k0, &Abuf[b][dA[r]]);
    #pragma unroll
    for (int r = 0; r < 2; ++r) {
      GLOAD16(srcB1[r] + k0, &B1buf[b][dB[r]]);
      GLOAD16(srcB2[r] + k0, &B2buf[b][dB[r]]);
    }
  };

  stage(0, 0);
  __syncthreads();

  for (int kt = 0; kt < 16; ++kt) {
    const int cur = kt & 1;
    if (kt + 1 < 16) stage(cur ^ 1, (kt + 1) * 64);
    #pragma unroll
    for (int ks = 0; ks < 2; ++ks) {
      const int kc = ks * 4 + kq;
      bf16x8 a[4], p[2], q[2];
      #pragma unroll
      for (int mi = 0; mi < 4; ++mi) {
        const int row = wm * 64 + mi * 16 + l15;
        a[mi] = *reinterpret_cast<const bf16x8*>(&Abuf[cur][row * 64 + ((kc ^ (row & 7)) << 3)]);
      }
      #pragma unroll
      for (int ni = 0; ni < 2; ++ni) {
        const int row = wn * 32 + ni * 16 + l15;
        const int ko = (kc ^ (row & 7)) << 3;
        p[ni] = *reinterpret_cast<const bf16x8*>(&B1buf[cur][row * 64 + ko]);
        q[ni] = *reinterpret_cast<const bf16x8*>(&B2buf[cur][row * 64 + ko]);
      }
      #pragma unroll
      for (int mi = 0; mi < 4; ++mi)
        #pragma unroll
        for (int ni = 0; ni < 2; ++ni) {
          acc1[mi][ni] = __builtin_amdgcn_mfma_f32_16x16x32_bf16(a[mi], p[ni], acc1[mi][ni], 0, 0, 0);
          acc2[mi][ni] = __builtin_amdgcn_mfma_f32_16x16x32_bf16(a[mi], q[ni], acc2[mi][ni], 0, 0, 0);
        }
    }
    __syncthreads();
  }

  const float* b1p = (g < NEXP) ? (rb1 + (size_t)g * HDIM) : (sb1 + (size_t)(g - NEXP) * HDIM);
  const float* b2p = (g < NEXP) ? (rb2 + (size_t)g * HDIM) : (sb2 + (size_t)(g - NEXP) * HDIM);

  #pragma unroll
  for (int mi = 0; mi < 4; ++mi) {
    #pragma unroll
    for (int r = 0; r < 4; ++r) {
      const int m = m0 + wm * 64 + mi * 16 + kq * 4 + r;
      if (m < n_g) {
        #pragma unroll
        for (int ni = 0; ni < 2; ++ni) {
          const int n = n0 + wn * 32 + ni * 16 + l15;
          const float x1 = acc1[mi][ni][r] + b1p[n];
          const float x2 = acc2[mi][ni][r] + b2p[n];
          glu[(size_t)(off_g + m) * HDIM + n] = f2bf((x1 / (1.f + expf(-x1))) * x2);
        }
      }
    }
  }
}

// ---- grouped GEMM 2: y = (glu W3 + b3) bf16, no atomics ----
// 128x128, BK=64, 256 thr (4 waves 2Mx2N), stage-early double-buffer,
// one barrier per K-tile.  LDS 64KB -> 2 blocks/CU.

__global__ __launch_bounds__(256, 2) void gemm2_kernel(
    const unsigned short* __restrict__ glu,
    const unsigned short* __restrict__ w3t,
    const float* __restrict__ rb3, const float* __restrict__ sb3,
    const int* __restrict__ offs,
    unsigned short* __restrict__ y) {
  const int g = blockIdx.z;
  const int off_g = offs[g];
  const int n_g = offs[g + 1] - off_g;
  const int m0 = blockIdx.x * 128;
  if (m0 >= n_g) return;
  const int n0 = blockIdx.y * 128;

  __shared__ __align__(16) unsigned short Abuf[2][128 * 64];
  __shared__ __align__(16) unsigned short Bbuf[2][128 * 64];

  const int tid = threadIdx.x;
  const int lane = tid & 63;
  const int wid = tid >> 6;
  const int wm = wid >> 1, wn = wid & 1;
  const int l15 = lane & 15, kq = lane >> 4;

  const unsigned short* w3g = w3t + (size_t)g * DMODEL * HDIM;

  const unsigned short* srcA[4]; const unsigned short* srcB[4]; int dAB[4];
  #pragma unroll
  for (int r = 0; r < 4; ++r) {
    const int chunk = r * 256 + tid, row = chunk >> 3, j = chunk & 7;
    int ar = m0 + row; if (ar > n_g - 1) ar = n_g - 1;
    srcA[r] = glu + (size_t)(off_g + ar) * HDIM + ((j ^ (row & 7)) << 3);
    srcB[r] = w3g + (size_t)(n0 + row) * HDIM + ((j ^ (row & 7)) << 3);
    dAB[r] = (r * 256 + (tid & ~63)) << 3;
  }

  f32x4 acc[4][4];
  const f32x4 zero = {0.f, 0.f, 0.f, 0.f};
  #pragma unroll
  for (int i = 0; i < 4; ++i)
    #pragma unroll
    for (int j = 0; j < 4; ++j) acc[i][j] = zero;

  auto stage = [&](int b, int k0) {
    #pragma unroll
    for (int r = 0; r < 4; ++r) {
      GLOAD16(srcA[r] + k0, &Abuf[b][dAB[r]]);
      GLOAD16(srcB[r] + k0, &Bbuf[b][dAB[r]]);
    }
  };

  stage(0, 0);
  __syncthreads();

  for (int kt = 0; kt < 32; ++kt) {
    const int cur = kt & 1;
    if (kt + 1 < 32) stage(cur ^ 1, (kt + 1) * 64);
    #pragma unroll
    for (int ks = 0; ks < 2; ++ks) {
      const int kc = ks * 4 + kq;
      bf16x8 a[4], b[4];
      #pragma unroll
      for (int mi = 0; mi < 4; ++mi) {
        const int row = wm * 64 + mi * 16 + l15;
        a[mi] = *reinterpret_cast<const bf16x8*>(&Abuf[cur][row * 64 + ((kc ^ (row & 7)) << 3)]);
      }
      #pragma unroll
      for (int ni = 0; ni < 4; ++ni) {
        const int row = wn * 64 + ni * 16 + l15;
        b[ni] = *reinterpret_cast<const bf16x8*>(&Bbuf[cur][row * 64 + ((kc ^ (row & 7)) << 3)]);
      }
      #pragma unroll
      for (int mi = 0; mi < 4; ++mi)
        #pragma unroll
        for (int ni = 0; ni < 4; ++ni)
          acc[mi][ni] = __builtin_amdgcn_mfma_f32_16x16x32_bf16(a[mi], b[ni], acc[mi][ni], 0, 0, 0);
    }
    __syncthreads();
  }

  const float* b3p = (g < NEXP) ? (rb3 + (size_t)g * DMODEL) : (sb3 + (size_t)(g - NEXP) * DMODEL);

  #pragma unroll
  for (int mi = 0; mi < 4; ++mi) {
    #pragma unroll
    for (int r = 0; r < 4; ++r) {
      const int m = m0 + wm * 64 + mi * 16 + kq * 4 + r;
      if (m < n_g) {
        unsigned short* yrow = y + (size_t)(off_g + m) * DMODEL;
        #pragma unroll
        for (int ni = 0; ni < 4; ++ni) {
          const int n = n0 + wn * 64 + ni * 16 + l15;
          yrow[n] = f2bf(acc[mi][ni][r] + b3p[n]);
        }
      }
    }
  }
}

// ---- reduce: out[t] = w0*y[r0] + w1*y[r1] + 0.5*y[sh0] + 0.5*y[sh1] ----

__global__ __launch_bounds__(256) void reduce_kernel(const unsigned short* __restrict__ y,
                                                     const int* __restrict__ tok_rows,
                                                     const float* __restrict__ topk_w,
                                                     float* __restrict__ out) {
  const int t = blockIdx.x * 2 + (threadIdx.x >> 7);
  const int col = (threadIdx.x & 127) * 8;
  const int r0 = tok_rows[t * 2 + 0], r1 = tok_rows[t * 2 + 1];
  const float w0 = topk_w[t * 2 + 0], w1 = topk_w[t * 2 + 1];

  float o[8];
  #pragma unroll
  for (int e = 0; e < 8; ++e) o[e] = 0.f;
  auto addrow = [&](const unsigned short* p, float w) {
    const u16x8 v = *reinterpret_cast<const u16x8*>(p);
    #pragma unroll
    for (int e = 0; e < 8; ++e) o[e] += w * bf2f(v[e]);
  };
  addrow(y + (size_t)r0 * DMODEL + col, w0);
  addrow(y + (size_t)r1 * DMODEL + col, w1);
  addrow(y + (size_t)(R_ROUTED + t) * DMODEL + col, 0.5f);
  addrow(y + (size_t)(R_ROUTED + TOKENS + t) * DMODEL + col, 0.5f);

  float4* op = reinterpret_cast<float4*>(out + (size_t)t * DMODEL + col);
  op[0] = make_float4(o[0], o[1], o[2], o[3]);
  op[1] = make_float4(o[4], o[5], o[6], o[7]);
}

// ---------------- launch ----------------

extern "C" void kernel_launch(void* const* d_in, const int* in_sizes, int n_in,
                              void* d_out, int out_size, void* d_ws, size_t ws_size,
                              hipStream_t stream) {
  const float* x      = (const float*)d_in[0];
  const float* gate_w = (const float*)d_in[1];
  const float* gate_b = (const float*)d_in[2];
  const float* rw1    = (const float*)d_in[3];
  const float* rb1    = (const float*)d_in[4];
  const float* rw2    = (const float*)d_in[5];
  const float* rb2    = (const float*)d_in[6];
  const float* rw3    = (const float*)d_in[7];
  const float* rb3    = (const float*)d_in[8];
  const float* sw1    = (const float*)d_in[9];
  const float* sb1    = (const float*)d_in[10];
  const float* sw2    = (const float*)d_in[11];
  const float* sb2    = (const float*)d_in[12];
  const float* sw3    = (const float*)d_in[13];
  const float* sb3    = (const float*)d_in[14];
  float* out = (float*)d_out;

  // workspace layout.  y ALIASES w1t/w2t (dead after gemm1; stream-ordered).
  const size_t XB_OFF   = 0;
  const size_t W1T_OFF  = XB_OFF  + (size_t)TOKENS * DMODEL * 2;
  const size_t W3T_OFF  = W1T_OFF + (size_t)2 * NGRP * HDIM * DMODEL * 2;
  const size_t GLU_OFF  = W3T_OFF + (size_t)NGRP * DMODEL * HDIM * 2;
  const size_t Y_OFF    = W1T_OFF;                       // alias over w1t/w2t
  const size_t RTOK_OFF = GLU_OFF + (size_t)R_TOTAL * HDIM * 2;
  const size_t TKI_OFF  = RTOK_OFF + (size_t)R_TOTAL * 4;
  const size_t TKW_OFF  = TKI_OFF + (size_t)TOKENS * 2 * 4;
  const size_t TRW_OFF  = TKW_OFF + (size_t)TOKENS * 2 * 4;
  const size_t META_OFF = TRW_OFF + (size_t)TOKENS * 2 * 4;
  const size_t NEED     = META_OFF + 256;
  if (ws_size < NEED) return;

  char* ws = (char*)d_ws;
  unsigned short* xb   = (unsigned short*)(ws + XB_OFF);
  unsigned short* w1t  = (unsigned short*)(ws + W1T_OFF);   // 20 mats: w1 (10) then w2 (10)
  unsigned short* w2t  = w1t + (size_t)NGRP * HDIM * DMODEL;
  unsigned short* w3t  = (unsigned short*)(ws + W3T_OFF);
  unsigned short* glu  = (unsigned short*)(ws + GLU_OFF);
  unsigned short* yy   = (unsigned short*)(ws + Y_OFF);
  int*   row_token = (int*)(ws + RTOK_OFF);
  int*   topk_idx  = (int*)(ws + TKI_OFF);
  float* topk_w    = (float*)(ws + TKW_OFF);
  int*   tok_rows  = (int*)(ws + TRW_OFF);
  int*   counts    = (int*)(ws + META_OFF);
  int*   offs      = counts + 16;
  int*   cursors   = counts + 32;

  hipMemsetAsync(counts, 0, 192, stream);

  transpose_cvt64_kernel<<<dim3(HDIM / 64, DMODEL / 64, 20), 256, 0, stream>>>(
      rw1, sw1, rw2, sw2, w1t, DMODEL, HDIM, 8, 2);
  transpose_cvt64_kernel<<<dim3(DMODEL / 64, HDIM / 64, 10), 256, 0, stream>>>(
      rw3, sw3, rw3, rw3, w3t, HDIM, DMODEL, 8, 2);

  gate_kernel<<<TOKENS / 4, 256, 0, stream>>>(x, gate_w, gate_b, topk_idx, topk_w, counts, xb);
  offs_kernel<<<1, 64, 0, stream>>>(counts, offs);
  scatter_kernel<<<TOKENS / 256, 256, 0, stream>>>(topk_idx, offs, cursors,
                                                   row_token, tok_rows);

  gemm1_kernel<<<dim3(TOKENS / 128, HDIM / 64, NGRP), 256, 0, stream>>>(
      xb, w1t, w2t, rb1, sb1, rb2, sb2, offs, row_token, glu);
  gemm2_kernel<<<dim3(TOKENS / 128, DMODEL / 128, NGRP), 256, 0, stream>>>(
      glu, w3t, rb3, sb3, offs, yy);
  reduce_kernel<<<TOKENS / 2, 256, 0, stream>>>(yy, tok_rows, topk_w, out);
}

// Round 13
// 889.465 us; speedup vs baseline: 1.8443x; 1.3961x over previous
//
#include <hip/hip_runtime.h>
#include <math.h>

#define TOKENS   8192
#define DMODEL   1024
#define HDIM     2048
#define NEXP     8
#define NSH      2
#define NGRP     10
#define R_ROUTED 16384
#define R_TOTAL  32768

typedef float  f32x4  __attribute__((ext_vector_type(4)));
typedef __bf16 bf16x8 __attribute__((ext_vector_type(8)));
typedef unsigned short u16x8 __attribute__((ext_vector_type(8)));

typedef __attribute__((address_space(1))) const void as1_void;
typedef __attribute__((address_space(3))) void as3_void;
#define GLOAD16(g, l) __builtin_amdgcn_global_load_lds((as1_void*)(g), (as3_void*)(l), 16, 0, 0)

__device__ __forceinline__ unsigned short f2bf(float f) {
  unsigned int u = __float_as_uint(f);
  u += 0x7fffu + ((u >> 16) & 1u);
  return (unsigned short)(u >> 16);
}
__device__ __forceinline__ float bf2f(unsigned short u) {
  return __uint_as_float(((unsigned int)u) << 16);
}

// ---- batched transpose fp32 (R x C) -> bf16 (C x R), 64x64 tiles ----
__global__ __launch_bounds__(256) void transpose_cvt64_kernel(
    const float* __restrict__ s0, const float* __restrict__ s1,
    const float* __restrict__ s2, const float* __restrict__ s3,
    unsigned short* __restrict__ dst, int R, int C, int n0, int n1) {
  __shared__ float tile[64][65];
  const int z = blockIdx.z;
  const size_t msz = (size_t)R * C;
  const float* src;
  if (z < n0) src = s0 + (size_t)z * msz;
  else if (z < n0 + n1) src = s1 + (size_t)(z - n0) * msz;
  else if (z < n0 + n1 + 8) src = s2 + (size_t)(z - n0 - n1) * msz;
  else src = s3 + (size_t)(z - n0 - n1 - 8) * msz;
  unsigned short* d = dst + (size_t)z * msz;

  const int c0 = blockIdx.x * 64, r0 = blockIdx.y * 64;
  const int tid = threadIdx.x;
  const int tx = tid & 15, ty = tid >> 4;
  #pragma unroll
  for (int rr = 0; rr < 4; ++rr) {
    const int row = ty + rr * 16;
    const float4 v = *reinterpret_cast<const float4*>(&src[(size_t)(r0 + row) * C + c0 + tx * 4]);
    tile[row][tx * 4 + 0] = v.x;
    tile[row][tx * 4 + 1] = v.y;
    tile[row][tx * 4 + 2] = v.z;
    tile[row][tx * 4 + 3] = v.w;
  }
  __syncthreads();
  const int oc = tid >> 2, og = tid & 3;
  u16x8 u0, u1;
  #pragma unroll
  for (int e = 0; e < 8; ++e) u0[e] = f2bf(tile[og * 16 + e][oc]);
  #pragma unroll
  for (int e = 0; e < 8; ++e) u1[e] = f2bf(tile[og * 16 + 8 + e][oc]);
  unsigned short* dp = &d[(size_t)(c0 + oc) * R + r0 + og * 16];
  *reinterpret_cast<u16x8*>(dp) = u0;
  *reinterpret_cast<u16x8*>(dp + 8) = u1;
}

// ---- gate + x->bf16 conversion fused.  4 tokens / 256-thr block ----

__global__ __launch_bounds__(256) void gate_kernel(const float* __restrict__ x,
                                                   const float* __restrict__ gw,
                                                   const float* __restrict__ gb,
                                                   int* __restrict__ topk_idx,
                                                   float* __restrict__ topk_w,
                                                   int* __restrict__ counts,
                                                   unsigned short* __restrict__ xb) {
  const int t = blockIdx.x * 4 + (threadIdx.x >> 6);
  const int lane = threadIdx.x & 63;
  const float* xr = x + (size_t)t * DMODEL;
  unsigned short* xbr = xb + (size_t)t * DMODEL;
  float acc[NEXP];
  #pragma unroll
  for (int e = 0; e < NEXP; ++e) acc[e] = 0.f;
  #pragma unroll
  for (int j = 0; j < 4; ++j) {
    const int d = j * 256 + lane * 4;
    const float4 v = *reinterpret_cast<const float4*>(&xr[d]);
    ushort4 o;
    o.x = f2bf(v.x); o.y = f2bf(v.y); o.z = f2bf(v.z); o.w = f2bf(v.w);
    *reinterpret_cast<ushort4*>(&xbr[d]) = o;
    #pragma unroll
    for (int q = 0; q < 4; ++q) {
      const float xv = (&v.x)[q];
      const float* g = gw + (size_t)(d + q) * NEXP;
      #pragma unroll
      for (int e = 0; e < NEXP; ++e) acc[e] += xv * g[e];
    }
  }
  #pragma unroll
  for (int e = 0; e < NEXP; ++e) {
    float v = acc[e];
    v += __shfl_down(v, 32); v += __shfl_down(v, 16); v += __shfl_down(v, 8);
    v += __shfl_down(v, 4);  v += __shfl_down(v, 2);  v += __shfl_down(v, 1);
    acc[e] = v;
  }
  if (lane == 0) {
    float p[NEXP];
    float mx = -1e30f;
    #pragma unroll
    for (int e = 0; e < NEXP; ++e) { acc[e] += gb[e]; mx = fmaxf(mx, acc[e]); }
    float s = 0.f;
    #pragma unroll
    for (int e = 0; e < NEXP; ++e) { p[e] = expf(acc[e] - mx); s += p[e]; }
    const float inv = 1.f / s;
    #pragma unroll
    for (int e = 0; e < NEXP; ++e) p[e] *= inv;
    int i1 = 0; float v1 = p[0];
    #pragma unroll
    for (int e = 1; e < NEXP; ++e) if (p[e] > v1) { v1 = p[e]; i1 = e; }
    int i2 = -1; float v2 = -1e30f;
    #pragma unroll
    for (int e = 0; e < NEXP; ++e) if (e != i1 && p[e] > v2) { v2 = p[e]; i2 = e; }
    topk_idx[t * 2 + 0] = i1; topk_w[t * 2 + 0] = v1;
    topk_idx[t * 2 + 1] = i2; topk_w[t * 2 + 1] = v2;
    atomicAdd(&counts[i1], 1);
    atomicAdd(&counts[i2], 1);
  }
}

__global__ void offs_kernel(const int* __restrict__ counts, int* __restrict__ offs) {
  if (threadIdx.x == 0 && blockIdx.x == 0) {
    int cum = 0;
    for (int e = 0; e < NEXP; ++e) { offs[e] = cum; cum += counts[e]; }
    offs[8] = R_ROUTED;
    offs[9] = R_ROUTED + TOKENS;
    offs[10] = R_TOTAL;
  }
}

__global__ __launch_bounds__(256) void scatter_kernel(const int* __restrict__ topk_idx,
                                                      const int* __restrict__ offs,
                                                      int* __restrict__ cursors,
                                                      int* __restrict__ row_token,
                                                      int* __restrict__ tok_rows) {
  const int t = blockIdx.x * blockDim.x + threadIdx.x;
  if (t >= TOKENS) return;
  #pragma unroll
  for (int k = 0; k < 2; ++k) {
    const int e = topk_idx[t * 2 + k];
    const int pos = atomicAdd(&cursors[e], 1);
    const int r = offs[e] + pos;
    row_token[r] = t;
    tok_rows[t * 2 + k] = r;
  }
  row_token[R_ROUTED + t] = t;
  row_token[R_ROUTED + TOKENS + t] = t;
}

// ---- grouped GEMM 1: glu = silu(X W1 + b1) * (X W2 + b2) ----
// EXACT R7 champion body (128m x 64n dual-B, BK=64, 256 thr, 4 waves 2Mx2N,
// single-buffer, 2 barriers/K-tile, 8-chunk XOR swizzle) + XCD-locality
// remap (T1): 1D grid, all 32 n-blocks of one (m,z) pair run consecutively
// on ONE XCD so the 256KB A-tile is re-read from that XCD's L2, not L3.
// Pairs interleaved mod 8 for live-work balance.  Bijection (20480 % 8 == 0).

__global__ __launch_bounds__(256, 3) void gemm1_kernel(
    const unsigned short* __restrict__ xb,
    const unsigned short* __restrict__ w1t,
    const unsigned short* __restrict__ w2t,
    const float* __restrict__ rb1, const float* __restrict__ sb1,
    const float* __restrict__ rb2, const float* __restrict__ sb2,
    const int* __restrict__ offs,
    const int* __restrict__ row_token,
    unsigned short* __restrict__ glu) {
  // decode: wgid -> (xcd, idx); pair=(idx/32)*8+xcd; y=idx%32; x=pair%64; g=pair/64
  const int wgid = blockIdx.x;
  const int xcd = wgid & 7, idx = wgid >> 3;
  const int pair = ((idx >> 5) << 3) + xcd;
  const int m0 = (pair & 63) * 128;
  const int g = pair >> 6;
  const int n0 = (idx & 31) * 64;

  const int off_g = offs[g];
  const int n_g = offs[g + 1] - off_g;
  if (m0 >= n_g) return;

  __shared__ __align__(16) unsigned short Abuf[128 * 64];
  __shared__ __align__(16) unsigned short B1buf[64 * 64];
  __shared__ __align__(16) unsigned short B2buf[64 * 64];

  const int tid = threadIdx.x;
  const int lane = tid & 63;
  const int wid = tid >> 6;
  const int wm = wid >> 1, wn = wid & 1;
  const int l15 = lane & 15, kq = lane >> 4;

  const unsigned short* w1g = w1t + (size_t)g * HDIM * DMODEL;
  const unsigned short* w2g = w2t + (size_t)g * HDIM * DMODEL;

  const unsigned short* srcA[4]; int dA[4];
  #pragma unroll
  for (int r = 0; r < 4; ++r) {
    const int chunk = r * 256 + tid, row = chunk >> 3, j = chunk & 7;
    int ar = m0 + row; if (ar > n_g - 1) ar = n_g - 1;
    srcA[r] = xb + (size_t)row_token[off_g + ar] * DMODEL + ((j ^ (row & 7)) << 3);
    dA[r] = (r * 256 + (tid & ~63)) << 3;
  }
  const unsigned short* srcB1[2]; const unsigned short* srcB2[2]; int dB[2];
  #pragma unroll
  for (int r = 0; r < 2; ++r) {
    const int chunk = r * 256 + tid, row = chunk >> 3, j = chunk & 7;
    const size_t o = (size_t)(n0 + row) * DMODEL + ((j ^ (row & 7)) << 3);
    srcB1[r] = w1g + o; srcB2[r] = w2g + o;
    dB[r] = (r * 256 + (tid & ~63)) << 3;
  }

  f32x4 acc1[4][2], acc2[4][2];
  const f32x4 zero = {0.f, 0.f, 0.f, 0.f};
  #pragma unroll
  for (int i = 0; i < 4; ++i)
    #pragma unroll
    for (int j = 0; j < 2; ++j) { acc1[i][j] = zero; acc2[i][j] = zero; }

  for (int k0 = 0; k0 < DMODEL; k0 += 64) {
    __syncthreads();
    #pragma unroll
    for (int r = 0; r < 4; ++r) GLOAD16(srcA[r] + k0, &Abuf[dA[r]]);
    #pragma unroll
    for (int r = 0; r < 2; ++r) {
      GLOAD16(srcB1[r] + k0, &B1buf[dB[r]]);
      GLOAD16(srcB2[r] + k0, &B2buf[dB[r]]);
    }
    __syncthreads();
    #pragma unroll
    for (int ks = 0; ks < 2; ++ks) {
      const int kc = ks * 4 + kq;
      bf16x8 a[4], p[2], q[2];
      #pragma unroll
      for (int mi = 0; mi < 4; ++mi) {
        const int row = wm * 64 + mi * 16 + l15;
        a[mi] = *reinterpret_cast<const bf16x8*>(&Abuf[row * 64 + ((kc ^ (row & 7)) << 3)]);
      }
      #pragma unroll
      for (int ni = 0; ni < 2; ++ni) {
        const int row = wn * 32 + ni * 16 + l15;
        const int ko = (kc ^ (row & 7)) << 3;
        p[ni] = *reinterpret_cast<const bf16x8*>(&B1buf[row * 64 + ko]);
        q[ni] = *reinterpret_cast<const bf16x8*>(&B2buf[row * 64 + ko]);
      }
      #pragma unroll
      for (int mi = 0; mi < 4; ++mi)
        #pragma unroll
        for (int ni = 0; ni < 2; ++ni) {
          acc1[mi][ni] = __builtin_amdgcn_mfma_f32_16x16x32_bf16(a[mi], p[ni], acc1[mi][ni], 0, 0, 0);
          acc2[mi][ni] = __builtin_amdgcn_mfma_f32_16x16x32_bf16(a[mi], q[ni], acc2[mi][ni], 0, 0, 0);
        }
    }
  }

  const float* b1p = (g < NEXP) ? (rb1 + (size_t)g * HDIM) : (sb1 + (size_t)(g - NEXP) * HDIM);
  const float* b2p = (g < NEXP) ? (rb2 + (size_t)g * HDIM) : (sb2 + (size_t)(g - NEXP) * HDIM);

  #pragma unroll
  for (int mi = 0; mi < 4; ++mi) {
    #pragma unroll
    for (int r = 0; r < 4; ++r) {
      const int m = m0 + wm * 64 + mi * 16 + kq * 4 + r;
      if (m < n_g) {
        #pragma unroll
        for (int ni = 0; ni < 2; ++ni) {
          const int n = n0 + wn * 32 + ni * 16 + l15;
          const float x1 = acc1[mi][ni][r] + b1p[n];
          const float x2 = acc2[mi][ni][r] + b2p[n];
          glu[(size_t)(off_g + m) * HDIM + n] = f2bf((x1 / (1.f + expf(-x1))) * x2);
        }
      }
    }
  }
}

// ---- grouped GEMM 2: y = (glu W3 + b3) bf16, no atomics ----
// EXACT R7 champion body (128x128, BK=64, 256 thr, single-buffer) + XCD
// remap: all 64 m-blocks of one (n,z) pair run consecutively on one XCD so
// the 512KB W3 panel is L2-resident.  Bijection (5120 % 8 == 0).

__global__ __launch_bounds__(256, 3) void gemm2_kernel(
    const unsigned short* __restrict__ glu,
    const unsigned short* __restrict__ w3t,
    const float* __restrict__ rb3, const float* __restrict__ sb3,
    const int* __restrict__ offs,
    unsigned short* __restrict__ y) {
  // decode: pair=(idx/64)*8+xcd over (y,z); x=idx%64
  const int wgid = blockIdx.x;
  const int xcd = wgid & 7, idx = wgid >> 3;
  const int pair = ((idx >> 6) << 3) + xcd;
  const int m0 = (idx & 63) * 128;
  const int n0 = (pair & 7) * 128;
  const int g = pair >> 3;

  const int off_g = offs[g];
  const int n_g = offs[g + 1] - off_g;
  if (m0 >= n_g) return;

  __shared__ __align__(16) unsigned short Abuf[128 * 64];
  __shared__ __align__(16) unsigned short Bbuf[128 * 64];

  const int tid = threadIdx.x;
  const int lane = tid & 63;
  const int wid = tid >> 6;
  const int wm = wid >> 1, wn = wid & 1;
  const int l15 = lane & 15, kq = lane >> 4;

  const unsigned short* w3g = w3t + (size_t)g * DMODEL * HDIM;

  const unsigned short* srcA[4]; const unsigned short* srcB[4]; int dAB[4];
  #pragma unroll
  for (int r = 0; r < 4; ++r) {
    const int chunk = r * 256 + tid, row = chunk >> 3, j = chunk & 7;
    int ar = m0 + row; if (ar > n_g - 1) ar = n_g - 1;
    srcA[r] = glu + (size_t)(off_g + ar) * HDIM + ((j ^ (row & 7)) << 3);
    srcB[r] = w3g + (size_t)(n0 + row) * HDIM + ((j ^ (row & 7)) << 3);
    dAB[r] = (r * 256 + (tid & ~63)) << 3;
  }

  f32x4 acc[4][4];
  const f32x4 zero = {0.f, 0.f, 0.f, 0.f};
  #pragma unroll
  for (int i = 0; i < 4; ++i)
    #pragma unroll
    for (int j = 0; j < 4; ++j) acc[i][j] = zero;

  for (int k0 = 0; k0 < HDIM; k0 += 64) {
    __syncthreads();
    #pragma unroll
    for (int r = 0; r < 4; ++r) {
      GLOAD16(srcA[r] + k0, &Abuf[dAB[r]]);
      GLOAD16(srcB[r] + k0, &Bbuf[dAB[r]]);
    }
    __syncthreads();
    #pragma unroll
    for (int ks = 0; ks < 2; ++ks) {
      const int kc = ks * 4 + kq;
      bf16x8 a[4], b[4];
      #pragma unroll
      for (int mi = 0; mi < 4; ++mi) {
        const int row = wm * 64 + mi * 16 + l15;
        a[mi] = *reinterpret_cast<const bf16x8*>(&Abuf[row * 64 + ((kc ^ (row & 7)) << 3)]);
      }
      #pragma unroll
      for (int ni = 0; ni < 4; ++ni) {
        const int row = wn * 64 + ni * 16 + l15;
        b[ni] = *reinterpret_cast<const bf16x8*>(&Bbuf[row * 64 + ((kc ^ (row & 7)) << 3)]);
      }
      #pragma unroll
      for (int mi = 0; mi < 4; ++mi)
        #pragma unroll
        for (int ni = 0; ni < 4; ++ni)
          acc[mi][ni] = __builtin_amdgcn_mfma_f32_16x16x32_bf16(a[mi], b[ni], acc[mi][ni], 0, 0, 0);
    }
  }

  const float* b3p = (g < NEXP) ? (rb3 + (size_t)g * DMODEL) : (sb3 + (size_t)(g - NEXP) * DMODEL);

  #pragma unroll
  for (int mi = 0; mi < 4; ++mi) {
    #pragma unroll
    for (int r = 0; r < 4; ++r) {
      const int m = m0 + wm * 64 + mi * 16 + kq * 4 + r;
      if (m < n_g) {
        unsigned short* yrow = y + (size_t)(off_g + m) * DMODEL;
        #pragma unroll
        for (int ni = 0; ni < 4; ++ni) {
          const int n = n0 + wn * 64 + ni * 16 + l15;
          yrow[n] = f2bf(acc[mi][ni][r] + b3p[n]);
        }
      }
    }
  }
}

// ---- reduce: out[t] = w0*y[r0] + w1*y[r1] + 0.5*y[sh0] + 0.5*y[sh1] ----

__global__ __launch_bounds__(256) void reduce_kernel(const unsigned short* __restrict__ y,
                                                     const int* __restrict__ tok_rows,
                                                     const float* __restrict__ topk_w,
                                                     float* __restrict__ out) {
  const int t = blockIdx.x * 2 + (threadIdx.x >> 7);
  const int col = (threadIdx.x & 127) * 8;
  const int r0 = tok_rows[t * 2 + 0], r1 = tok_rows[t * 2 + 1];
  const float w0 = topk_w[t * 2 + 0], w1 = topk_w[t * 2 + 1];

  float o[8];
  #pragma unroll
  for (int e = 0; e < 8; ++e) o[e] = 0.f;
  auto addrow = [&](const unsigned short* p, float w) {
    const u16x8 v = *reinterpret_cast<const u16x8*>(p);
    #pragma unroll
    for (int e = 0; e < 8; ++e) o[e] += w * bf2f(v[e]);
  };
  addrow(y + (size_t)r0 * DMODEL + col, w0);
  addrow(y + (size_t)r1 * DMODEL + col, w1);
  addrow(y + (size_t)(R_ROUTED + t) * DMODEL + col, 0.5f);
  addrow(y + (size_t)(R_ROUTED + TOKENS + t) * DMODEL + col, 0.5f);

  float4* op = reinterpret_cast<float4*>(out + (size_t)t * DMODEL + col);
  op[0] = make_float4(o[0], o[1], o[2], o[3]);
  op[1] = make_float4(o[4], o[5], o[6], o[7]);
}

// ---------------- launch ----------------

extern "C" void kernel_launch(void* const* d_in, const int* in_sizes, int n_in,
                              void* d_out, int out_size, void* d_ws, size_t ws_size,
                              hipStream_t stream) {
  const float* x      = (const float*)d_in[0];
  const float* gate_w = (const float*)d_in[1];
  const float* gate_b = (const float*)d_in[2];
  const float* rw1    = (const float*)d_in[3];
  const float* rb1    = (const float*)d_in[4];
  const float* rw2    = (const float*)d_in[5];
  const float* rb2    = (const float*)d_in[6];
  const float* rw3    = (const float*)d_in[7];
  const float* rb3    = (const float*)d_in[8];
  const float* sw1    = (const float*)d_in[9];
  const float* sb1    = (const float*)d_in[10];
  const float* sw2    = (const float*)d_in[11];
  const float* sb2    = (const float*)d_in[12];
  const float* sw3    = (const float*)d_in[13];
  const float* sb3    = (const float*)d_in[14];
  float* out = (float*)d_out;

  // workspace layout.  y ALIASES w1t/w2t (dead after gemm1; stream-ordered).
  const size_t XB_OFF   = 0;
  const size_t W1T_OFF  = XB_OFF  + (size_t)TOKENS * DMODEL * 2;
  const size_t W3T_OFF  = W1T_OFF + (size_t)2 * NGRP * HDIM * DMODEL * 2;
  const size_t GLU_OFF  = W3T_OFF + (size_t)NGRP * DMODEL * HDIM * 2;
  const size_t Y_OFF    = W1T_OFF;                       // alias over w1t/w2t
  const size_t RTOK_OFF = GLU_OFF + (size_t)R_TOTAL * HDIM * 2;
  const size_t TKI_OFF  = RTOK_OFF + (size_t)R_TOTAL * 4;
  const size_t TKW_OFF  = TKI_OFF + (size_t)TOKENS * 2 * 4;
  const size_t TRW_OFF  = TKW_OFF + (size_t)TOKENS * 2 * 4;
  const size_t META_OFF = TRW_OFF + (size_t)TOKENS * 2 * 4;
  const size_t NEED     = META_OFF + 256;
  if (ws_size < NEED) return;

  char* ws = (char*)d_ws;
  unsigned short* xb   = (unsigned short*)(ws + XB_OFF);
  unsigned short* w1t  = (unsigned short*)(ws + W1T_OFF);   // 20 mats: w1 (10) then w2 (10)
  unsigned short* w2t  = w1t + (size_t)NGRP * HDIM * DMODEL;
  unsigned short* w3t  = (unsigned short*)(ws + W3T_OFF);
  unsigned short* glu  = (unsigned short*)(ws + GLU_OFF);
  unsigned short* yy   = (unsigned short*)(ws + Y_OFF);
  int*   row_token = (int*)(ws + RTOK_OFF);
  int*   topk_idx  = (int*)(ws + TKI_OFF);
  float* topk_w    = (float*)(ws + TKW_OFF);
  int*   tok_rows  = (int*)(ws + TRW_OFF);
  int*   counts    = (int*)(ws + META_OFF);
  int*   offs      = counts + 16;
  int*   cursors   = counts + 32;

  hipMemsetAsync(counts, 0, 192, stream);

  transpose_cvt64_kernel<<<dim3(HDIM / 64, DMODEL / 64, 20), 256, 0, stream>>>(
      rw1, sw1, rw2, sw2, w1t, DMODEL, HDIM, 8, 2);
  transpose_cvt64_kernel<<<dim3(DMODEL / 64, HDIM / 64, 10), 256, 0, stream>>>(
      rw3, sw3, rw3, rw3, w3t, HDIM, DMODEL, 8, 2);

  gate_kernel<<<TOKENS / 4, 256, 0, stream>>>(x, gate_w, gate_b, topk_idx, topk_w, counts, xb);
  offs_kernel<<<1, 64, 0, stream>>>(counts, offs);
  scatter_kernel<<<TOKENS / 256, 256, 0, stream>>>(topk_idx, offs, cursors,
                                                   row_token, tok_rows);

  // 1D grids with in-kernel XCD-locality decode (see kernel comments)
  gemm1_kernel<<<(TOKENS / 128) * (HDIM / 64) * NGRP, 256, 0, stream>>>(
      xb, w1t, w2t, rb1, sb1, rb2, sb2, offs, row_token, glu);
  gemm2_kernel<<<(TOKENS / 128) * (DMODEL / 128) * NGRP, 256, 0, stream>>>(
      glu, w3t, rb3, sb3, offs, yy);
  reduce_kernel<<<TOKENS / 2, 256, 0, stream>>>(yy, tok_rows, topk_w, out);
}